// Round 1
// baseline (3303.450 us; speedup 1.0000x reference)
//
#include <hip/hip_runtime.h>

#define NN 1024
#define KK 128

// ---------------------------------------------------------------------------
// Sandwich kernel: Out_n = B_n^T (A_n B_n)  [+ epilogue for FINAL]
// One block per n. 256 threads, 8x8 register tile each.
// T (the intermediate A@B) lives in LDS, so FINAL can be in-place (A == Out).
// ---------------------------------------------------------------------------
template<bool FINAL>
__global__ __launch_bounds__(256) void sandwich_kernel(
    const float* __restrict__ A_, const float* __restrict__ B_,
    float* __restrict__ Out,
    const float* __restrict__ Lp, const float* __restrict__ Lq,
    const float* __restrict__ obs, const float* __restrict__ beta)
{
    __shared__ float T[128 * 132];   // [r][c], stride 132
    __shared__ float Ap[32 * 132];   // A^T panel: [kk][r], stride 132
    __shared__ float Bp[32 * 128];   // B panel:   [kk][c], stride 128
    __shared__ float wred[4];
    __shared__ float cs_sh;

    const int n   = blockIdx.x;
    const int tid = threadIdx.x;
    const int tr  = tid >> 4;        // 0..15
    const int tc  = tid & 15;        // 0..15
    const int r0  = tr * 8;
    const int c0  = tc * 8;
    const size_t base = (size_t)n * (KK * KK);

    // ---- column sum of beta (excluding diagonal), FINAL only ----
    if (FINAL) {
        float s = 0.f;
        for (int j = tid; j < NN; j += 256)
            if (j != n) s += beta[(size_t)j * NN + n];
        #pragma unroll
        for (int off = 32; off >= 1; off >>= 1) s += __shfl_down(s, off);
        if ((tid & 63) == 0) wred[tid >> 6] = s;
        __syncthreads();
        if (tid == 0) cs_sh = wred[0] + wred[1] + wred[2] + wred[3];
        __syncthreads();
    }

    float acc[8][8];
    #pragma unroll
    for (int m = 0; m < 8; ++m)
        #pragma unroll
        for (int e = 0; e < 8; ++e) acc[m][e] = 0.f;

    // ================= stage 1: T = A @ B =================
    for (int kp = 0; kp < 4; ++kp) {
        const int k0 = kp * 32;
        // load A^T panel
        #pragma unroll
        for (int it = 0; it < 4; ++it) {
            int idx = it * 256 + tid;
            int r = idx >> 3;
            int kk = (idx & 7) << 2;
            float4 v = *(const float4*)(A_ + base + (size_t)r * KK + k0 + kk);
            Ap[(kk + 0) * 132 + r] = v.x;
            Ap[(kk + 1) * 132 + r] = v.y;
            Ap[(kk + 2) * 132 + r] = v.z;
            Ap[(kk + 3) * 132 + r] = v.w;
        }
        // load B panel
        #pragma unroll
        for (int it = 0; it < 4; ++it) {
            int idx = it * 256 + tid;
            int kk = idx >> 5;
            int c  = (idx & 31) << 2;
            *(float4*)&Bp[kk * 128 + c] =
                *(const float4*)(B_ + base + (size_t)(k0 + kk) * KK + c);
        }
        __syncthreads();
        #pragma unroll 8
        for (int kk = 0; kk < 32; ++kk) {
            float4 a0 = *(const float4*)&Ap[kk * 132 + r0];
            float4 a1 = *(const float4*)&Ap[kk * 132 + r0 + 4];
            float4 b0 = *(const float4*)&Bp[kk * 128 + c0];
            float4 b1 = *(const float4*)&Bp[kk * 128 + c0 + 4];
            float av[8] = {a0.x, a0.y, a0.z, a0.w, a1.x, a1.y, a1.z, a1.w};
            float bv[8] = {b0.x, b0.y, b0.z, b0.w, b1.x, b1.y, b1.z, b1.w};
            #pragma unroll
            for (int m = 0; m < 8; ++m)
                #pragma unroll
                for (int e = 0; e < 8; ++e)
                    acc[m][e] = fmaf(av[m], bv[e], acc[m][e]);
        }
        __syncthreads();
    }
    // write T
    #pragma unroll
    for (int m = 0; m < 8; ++m) {
        *(float4*)&T[(r0 + m) * 132 + c0] =
            make_float4(acc[m][0], acc[m][1], acc[m][2], acc[m][3]);
        *(float4*)&T[(r0 + m) * 132 + c0 + 4] =
            make_float4(acc[m][4], acc[m][5], acc[m][6], acc[m][7]);
    }
    __syncthreads();

    // ================= stage 2: Out = B^T @ T =================
    #pragma unroll
    for (int m = 0; m < 8; ++m)
        #pragma unroll
        for (int e = 0; e < 8; ++e) acc[m][e] = 0.f;

    for (int kp = 0; kp < 4; ++kp) {
        const int k0 = kp * 32;
        #pragma unroll
        for (int it = 0; it < 4; ++it) {
            int idx = it * 256 + tid;
            int kk = idx >> 5;
            int c  = (idx & 31) << 2;
            *(float4*)&Bp[kk * 128 + c] =
                *(const float4*)(B_ + base + (size_t)(k0 + kk) * KK + c);
        }
        __syncthreads();
        #pragma unroll 8
        for (int kk = 0; kk < 32; ++kk) {
            // a = B[k][r0..r0+7], b = T[k][c0..c0+7]
            float4 a0 = *(const float4*)&Bp[kk * 128 + r0];
            float4 a1 = *(const float4*)&Bp[kk * 128 + r0 + 4];
            float4 b0 = *(const float4*)&T[(k0 + kk) * 132 + c0];
            float4 b1 = *(const float4*)&T[(k0 + kk) * 132 + c0 + 4];
            float av[8] = {a0.x, a0.y, a0.z, a0.w, a1.x, a1.y, a1.z, a1.w};
            float bv[8] = {b0.x, b0.y, b0.z, b0.w, b1.x, b1.y, b1.z, b1.w};
            #pragma unroll
            for (int m = 0; m < 8; ++m)
                #pragma unroll
                for (int e = 0; e < 8; ++e)
                    acc[m][e] = fmaf(av[m], bv[e], acc[m][e]);
        }
        __syncthreads();
    }

    // ================= epilogue + store =================
    const float csv = FINAL ? cs_sh : 0.f;
    #pragma unroll
    for (int m = 0; m < 8; ++m) {
        const int row = r0 + m;
        float o[8];
        #pragma unroll
        for (int e = 0; e < 8; ++e) o[e] = acc[m][e];
        if (FINAL) {
            float4 lp0 = *(const float4*)(Lp + base + (size_t)row * KK + c0);
            float4 lp1 = *(const float4*)(Lp + base + (size_t)row * KK + c0 + 4);
            float4 lq0 = *(const float4*)(Lq + base + (size_t)row * KK + c0);
            float4 lq1 = *(const float4*)(Lq + base + (size_t)row * KK + c0 + 4);
            float4 ob0 = *(const float4*)(obs + (size_t)row * KK + c0);
            float4 ob1 = *(const float4*)(obs + (size_t)row * KK + c0 + 4);
            o[0] += lp0.x + csv * lq0.x + ob0.x;
            o[1] += lp0.y + csv * lq0.y + ob0.y;
            o[2] += lp0.z + csv * lq0.z + ob0.z;
            o[3] += lp0.w + csv * lq0.w + ob0.w;
            o[4] += lp1.x + csv * lq1.x + ob1.x;
            o[5] += lp1.y + csv * lq1.y + ob1.y;
            o[6] += lp1.z + csv * lq1.z + ob1.z;
            o[7] += lp1.w + csv * lq1.w + ob1.w;
        }
        *(float4*)(Out + base + (size_t)row * KK + c0) =
            make_float4(o[0], o[1], o[2], o[3]);
        *(float4*)(Out + base + (size_t)row * KK + c0 + 4) =
            make_float4(o[4], o[5], o[6], o[7]);
    }
}

// ---------------------------------------------------------------------------
// Big GEMM: W[i][c] = sum_k beta_nd[i][k] * S[k][c]   (M=1024, N=16384, K=1024)
// grid (128, 8): x = 128-wide column tile, y = 128-wide row tile
// ---------------------------------------------------------------------------
__global__ __launch_bounds__(256) void gemm_beta_kernel(
    const float* __restrict__ beta, const float* __restrict__ S,
    float* __restrict__ W)
{
    __shared__ float Ap[32 * 132];   // beta^T panel [kk][i]
    __shared__ float Bp[32 * 128];   // S panel [kk][c]

    const int tid = threadIdx.x;
    const int tr  = tid >> 4, tc = tid & 15;
    const int r0  = tr * 8, c0 = tc * 8;
    const int i0  = blockIdx.y * 128;
    const size_t cbase = (size_t)blockIdx.x * 128;

    float acc[8][8];
    #pragma unroll
    for (int m = 0; m < 8; ++m)
        #pragma unroll
        for (int e = 0; e < 8; ++e) acc[m][e] = 0.f;

    for (int kp = 0; kp < 32; ++kp) {
        const int k0 = kp * 32;
        #pragma unroll
        for (int it = 0; it < 4; ++it) {
            int idx = it * 256 + tid;
            int r = idx >> 3;
            int kk = (idx & 7) << 2;
            int gi = i0 + r;
            float4 v = *(const float4*)(beta + (size_t)gi * NN + k0 + kk);
            // zero the diagonal of beta
            if (gi == k0 + kk + 0) v.x = 0.f;
            if (gi == k0 + kk + 1) v.y = 0.f;
            if (gi == k0 + kk + 2) v.z = 0.f;
            if (gi == k0 + kk + 3) v.w = 0.f;
            Ap[(kk + 0) * 132 + r] = v.x;
            Ap[(kk + 1) * 132 + r] = v.y;
            Ap[(kk + 2) * 132 + r] = v.z;
            Ap[(kk + 3) * 132 + r] = v.w;
        }
        #pragma unroll
        for (int it = 0; it < 4; ++it) {
            int idx = it * 256 + tid;
            int kk = idx >> 5;
            int c  = (idx & 31) << 2;
            *(float4*)&Bp[kk * 128 + c] =
                *(const float4*)(S + (size_t)(k0 + kk) * 16384 + cbase + c);
        }
        __syncthreads();
        #pragma unroll 8
        for (int kk = 0; kk < 32; ++kk) {
            float4 a0 = *(const float4*)&Ap[kk * 132 + r0];
            float4 a1 = *(const float4*)&Ap[kk * 132 + r0 + 4];
            float4 b0 = *(const float4*)&Bp[kk * 128 + c0];
            float4 b1 = *(const float4*)&Bp[kk * 128 + c0 + 4];
            float av[8] = {a0.x, a0.y, a0.z, a0.w, a1.x, a1.y, a1.z, a1.w};
            float bv[8] = {b0.x, b0.y, b0.z, b0.w, b1.x, b1.y, b1.z, b1.w};
            #pragma unroll
            for (int m = 0; m < 8; ++m)
                #pragma unroll
                for (int e = 0; e < 8; ++e)
                    acc[m][e] = fmaf(av[m], bv[e], acc[m][e]);
        }
        __syncthreads();
    }
    #pragma unroll
    for (int m = 0; m < 8; ++m) {
        *(float4*)(W + (size_t)(i0 + r0 + m) * 16384 + cbase + c0) =
            make_float4(acc[m][0], acc[m][1], acc[m][2], acc[m][3]);
        *(float4*)(W + (size_t)(i0 + r0 + m) * 16384 + cbase + c0 + 4) =
            make_float4(acc[m][4], acc[m][5], acc[m][6], acc[m][7]);
    }
}

// ---------------------------------------------------------------------------
// Batched 128x128 inverse, Gauss-Jordan with partial pivoting.
// One block per matrix; matrix lives in registers (thread owns 4 rows x 16 cols).
// ---------------------------------------------------------------------------
__global__ __launch_bounds__(256) void invert_kernel(
    const float* __restrict__ Om, float* __restrict__ Inv)
{
    const int n   = blockIdx.x;
    const int tid = threadIdx.x;
    const int rg  = tid >> 3;   // 0..31  (4 rows each)
    const int cc  = tid & 7;    // 0..7   (16 cols each)
    const int r0  = rg << 2;
    const int c0  = cc << 4;
    const size_t base = (size_t)n * (KK * KK);

    float a[4][16];
    #pragma unroll
    for (int m = 0; m < 4; ++m)
        #pragma unroll
        for (int j4 = 0; j4 < 4; ++j4) {
            float4 v = *(const float4*)(Om + base + (size_t)(r0 + m) * KK + c0 + j4 * 4);
            a[m][j4 * 4 + 0] = v.x; a[m][j4 * 4 + 1] = v.y;
            a[m][j4 * 4 + 2] = v.z; a[m][j4 * 4 + 3] = v.w;
        }

    __shared__ float colk[128];
    __shared__ float rowk[128];
    __shared__ float rowswap[128];
    __shared__ int   perm[128];
    __shared__ int   piv_sh;
    __shared__ float pv_sh;

    for (int k = 0; k < 128; ++k) {
        const int kcc = k >> 4, kj = k & 15, krg = k >> 2, km = k & 3;
        // publish current column k
        if (cc == kcc) {
            #pragma unroll
            for (int m = 0; m < 4; ++m) colk[r0 + m] = a[m][kj];
        }
        __syncthreads();
        // pivot search (wave 0)
        if (tid < 64) {
            float best = -1.f; int bi = k;
            for (int i = k + tid; i < 128; i += 64) {
                float v = fabsf(colk[i]);
                if (v > best) { best = v; bi = i; }
            }
            #pragma unroll
            for (int off = 32; off >= 1; off >>= 1) {
                float ov = __shfl_down(best, off);
                int   oi = __shfl_down(bi, off);
                if (ov > best) { best = ov; bi = oi; }
            }
            if (tid == 0) { piv_sh = bi; pv_sh = colk[bi]; perm[k] = bi; }
        }
        __syncthreads();
        const int   r      = piv_sh;
        const float pivinv = 1.0f / pv_sh;
        // swap rows k and r (block-uniform branch)
        if (r != k) {
            const int rrg = r >> 2, rm = r & 3;
            if (rg == krg) {
                #pragma unroll
                for (int j = 0; j < 16; ++j) rowk[c0 + j] = a[km][j];
            }
            if (rg == rrg) {
                #pragma unroll
                for (int j = 0; j < 16; ++j) rowswap[c0 + j] = a[rm][j];
            }
            __syncthreads();
            if (rg == krg) {
                #pragma unroll
                for (int j = 0; j < 16; ++j) a[km][j] = rowswap[c0 + j];
            }
            if (rg == rrg) {
                #pragma unroll
                for (int j = 0; j < 16; ++j) a[rm][j] = rowk[c0 + j];
            }
            if (tid == 0) { float t = colk[k]; colk[k] = colk[r]; colk[r] = t; }
            __syncthreads();
        }
        // scale pivot row, publish it
        if (rg == krg) {
            #pragma unroll
            for (int j = 0; j < 16; ++j) {
                int jg = c0 + j;
                float v = (jg == k) ? pivinv : a[km][j] * pivinv;
                a[km][j] = v;
                rowk[jg] = v;
            }
        }
        __syncthreads();
        // rank-1 update of all other rows
        float rk[16];
        #pragma unroll
        for (int j = 0; j < 16; ++j) rk[j] = rowk[c0 + j];
        #pragma unroll
        for (int m = 0; m < 4; ++m) {
            int l = r0 + m;
            if (l == k) continue;
            float f = colk[l];
            #pragma unroll
            for (int j = 0; j < 16; ++j) {
                int jg = c0 + j;
                float v = (jg == k) ? 0.f : a[m][j];
                a[m][j] = fmaf(-f, rk[j], v);
            }
        }
        __syncthreads();
    }

    // column unscramble (undo row pivots)
    __shared__ int pos_sh[128];
    if (tid == 0) {
        int idxa[128];
        for (int j = 0; j < 128; ++j) idxa[j] = j;
        for (int l = 127; l >= 0; --l) {
            int p = perm[l];
            if (p != l) { int t = idxa[l]; idxa[l] = idxa[p]; idxa[p] = t; }
        }
        for (int j = 0; j < 128; ++j) pos_sh[idxa[j]] = j;
    }
    __syncthreads();
    float* dst = Inv + base;
    #pragma unroll
    for (int m = 0; m < 4; ++m)
        #pragma unroll
        for (int j = 0; j < 16; ++j)
            dst[(size_t)(r0 + m) * KK + pos_sh[c0 + j]] = a[m][j];
}

// ---------------------------------------------------------------------------
extern "C" void kernel_launch(void* const* d_in, const int* in_sizes, int n_in,
                              void* d_out, int out_size, void* d_ws, size_t ws_size,
                              hipStream_t stream)
{
    const float* beta  = (const float*)d_in[0];
    const float* omega = (const float*)d_in[1];
    const float* Lp    = (const float*)d_in[2];
    const float* Lq    = (const float*)d_in[3];
    const float* obs   = (const float*)d_in[4];
    float* out = (float*)d_out;

    const size_t MATE = (size_t)NN * KK * KK;  // elements of one (N,K,K) tensor
    float* S = (float*)d_ws;
    float* Wbuf = (ws_size >= 2 * MATE * sizeof(float)) ? (S + MATE) : out;
    float* Inv = S;  // reuse S space after the big GEMM consumed S

    // 1. S_n = Omega_n^T Lq_n Omega_n
    sandwich_kernel<false><<<dim3(NN), dim3(256), 0, stream>>>(
        Lq, omega, S, nullptr, nullptr, nullptr, nullptr);
    // 2. W = beta_nd @ S
    gemm_beta_kernel<<<dim3(128, 8), dim3(256), 0, stream>>>(beta, S, Wbuf);
    // 3. Inv_n = Omega_n^{-1}
    invert_kernel<<<dim3(NN), dim3(256), 0, stream>>>(omega, Inv);
    // 4. M_n = Inv_n^T W_n Inv_n + Lp_n + colsum_n * Lq_n + obs  (in-place safe)
    sandwich_kernel<true><<<dim3(NN), dim3(256), 0, stream>>>(
        Wbuf, Inv, out, Lp, Lq, obs, beta);
}

// Round 2
// 1227.583 us; speedup vs baseline: 2.6910x; 2.6910x over previous
//
#include <hip/hip_runtime.h>

#define NN 1024
#define KK 128

// ---------------------------------------------------------------------------
// Sandwich kernel: Out_n = B_n^T (A_n B_n)  [+ epilogue for FINAL]
// One block per n. 256 threads, 8x8 register tile each.
// T (the intermediate A@B) lives in LDS, so FINAL can be in-place (A == Out).
// ---------------------------------------------------------------------------
template<bool FINAL>
__global__ __launch_bounds__(256) void sandwich_kernel(
    const float* __restrict__ A_, const float* __restrict__ B_,
    float* __restrict__ Out,
    const float* __restrict__ Lp, const float* __restrict__ Lq,
    const float* __restrict__ obs, const float* __restrict__ beta)
{
    __shared__ float T[128 * 132];   // [r][c], stride 132
    __shared__ float Ap[32 * 132];   // A^T panel: [kk][r], stride 132
    __shared__ float Bp[32 * 128];   // B panel:   [kk][c], stride 128
    __shared__ float wred[4];
    __shared__ float cs_sh;

    const int n   = blockIdx.x;
    const int tid = threadIdx.x;
    const int tr  = tid >> 4;        // 0..15
    const int tc  = tid & 15;        // 0..15
    const int r0  = tr * 8;
    const int c0  = tc * 8;
    const size_t base = (size_t)n * (KK * KK);

    // ---- column sum of beta (excluding diagonal), FINAL only ----
    if (FINAL) {
        float s = 0.f;
        for (int j = tid; j < NN; j += 256)
            if (j != n) s += beta[(size_t)j * NN + n];
        #pragma unroll
        for (int off = 32; off >= 1; off >>= 1) s += __shfl_down(s, off);
        if ((tid & 63) == 0) wred[tid >> 6] = s;
        __syncthreads();
        if (tid == 0) cs_sh = wred[0] + wred[1] + wred[2] + wred[3];
        __syncthreads();
    }

    float acc[8][8];
    #pragma unroll
    for (int m = 0; m < 8; ++m)
        #pragma unroll
        for (int e = 0; e < 8; ++e) acc[m][e] = 0.f;

    // ================= stage 1: T = A @ B =================
    for (int kp = 0; kp < 4; ++kp) {
        const int k0 = kp * 32;
        // load A^T panel
        #pragma unroll
        for (int it = 0; it < 4; ++it) {
            int idx = it * 256 + tid;
            int r = idx >> 3;
            int kk = (idx & 7) << 2;
            float4 v = *(const float4*)(A_ + base + (size_t)r * KK + k0 + kk);
            Ap[(kk + 0) * 132 + r] = v.x;
            Ap[(kk + 1) * 132 + r] = v.y;
            Ap[(kk + 2) * 132 + r] = v.z;
            Ap[(kk + 3) * 132 + r] = v.w;
        }
        // load B panel
        #pragma unroll
        for (int it = 0; it < 4; ++it) {
            int idx = it * 256 + tid;
            int kk = idx >> 5;
            int c  = (idx & 31) << 2;
            *(float4*)&Bp[kk * 128 + c] =
                *(const float4*)(B_ + base + (size_t)(k0 + kk) * KK + c);
        }
        __syncthreads();
        #pragma unroll 8
        for (int kk = 0; kk < 32; ++kk) {
            float4 a0 = *(const float4*)&Ap[kk * 132 + r0];
            float4 a1 = *(const float4*)&Ap[kk * 132 + r0 + 4];
            float4 b0 = *(const float4*)&Bp[kk * 128 + c0];
            float4 b1 = *(const float4*)&Bp[kk * 128 + c0 + 4];
            float av[8] = {a0.x, a0.y, a0.z, a0.w, a1.x, a1.y, a1.z, a1.w};
            float bv[8] = {b0.x, b0.y, b0.z, b0.w, b1.x, b1.y, b1.z, b1.w};
            #pragma unroll
            for (int m = 0; m < 8; ++m)
                #pragma unroll
                for (int e = 0; e < 8; ++e)
                    acc[m][e] = fmaf(av[m], bv[e], acc[m][e]);
        }
        __syncthreads();
    }
    // write T
    #pragma unroll
    for (int m = 0; m < 8; ++m) {
        *(float4*)&T[(r0 + m) * 132 + c0] =
            make_float4(acc[m][0], acc[m][1], acc[m][2], acc[m][3]);
        *(float4*)&T[(r0 + m) * 132 + c0 + 4] =
            make_float4(acc[m][4], acc[m][5], acc[m][6], acc[m][7]);
    }
    __syncthreads();

    // ================= stage 2: Out = B^T @ T =================
    #pragma unroll
    for (int m = 0; m < 8; ++m)
        #pragma unroll
        for (int e = 0; e < 8; ++e) acc[m][e] = 0.f;

    for (int kp = 0; kp < 4; ++kp) {
        const int k0 = kp * 32;
        #pragma unroll
        for (int it = 0; it < 4; ++it) {
            int idx = it * 256 + tid;
            int kk = idx >> 5;
            int c  = (idx & 31) << 2;
            *(float4*)&Bp[kk * 128 + c] =
                *(const float4*)(B_ + base + (size_t)(k0 + kk) * KK + c);
        }
        __syncthreads();
        #pragma unroll 8
        for (int kk = 0; kk < 32; ++kk) {
            // a = B[k][r0..r0+7], b = T[k][c0..c0+7]
            float4 a0 = *(const float4*)&Bp[kk * 128 + r0];
            float4 a1 = *(const float4*)&Bp[kk * 128 + r0 + 4];
            float4 b0 = *(const float4*)&T[(k0 + kk) * 132 + c0];
            float4 b1 = *(const float4*)&T[(k0 + kk) * 132 + c0 + 4];
            float av[8] = {a0.x, a0.y, a0.z, a0.w, a1.x, a1.y, a1.z, a1.w};
            float bv[8] = {b0.x, b0.y, b0.z, b0.w, b1.x, b1.y, b1.z, b1.w};
            #pragma unroll
            for (int m = 0; m < 8; ++m)
                #pragma unroll
                for (int e = 0; e < 8; ++e)
                    acc[m][e] = fmaf(av[m], bv[e], acc[m][e]);
        }
        __syncthreads();
    }

    // ================= epilogue + store =================
    const float csv = FINAL ? cs_sh : 0.f;
    #pragma unroll
    for (int m = 0; m < 8; ++m) {
        const int row = r0 + m;
        float o[8];
        #pragma unroll
        for (int e = 0; e < 8; ++e) o[e] = acc[m][e];
        if (FINAL) {
            float4 lp0 = *(const float4*)(Lp + base + (size_t)row * KK + c0);
            float4 lp1 = *(const float4*)(Lp + base + (size_t)row * KK + c0 + 4);
            float4 lq0 = *(const float4*)(Lq + base + (size_t)row * KK + c0);
            float4 lq1 = *(const float4*)(Lq + base + (size_t)row * KK + c0 + 4);
            float4 ob0 = *(const float4*)(obs + (size_t)row * KK + c0);
            float4 ob1 = *(const float4*)(obs + (size_t)row * KK + c0 + 4);
            o[0] += lp0.x + csv * lq0.x + ob0.x;
            o[1] += lp0.y + csv * lq0.y + ob0.y;
            o[2] += lp0.z + csv * lq0.z + ob0.z;
            o[3] += lp0.w + csv * lq0.w + ob0.w;
            o[4] += lp1.x + csv * lq1.x + ob1.x;
            o[5] += lp1.y + csv * lq1.y + ob1.y;
            o[6] += lp1.z + csv * lq1.z + ob1.z;
            o[7] += lp1.w + csv * lq1.w + ob1.w;
        }
        *(float4*)(Out + base + (size_t)row * KK + c0) =
            make_float4(o[0], o[1], o[2], o[3]);
        *(float4*)(Out + base + (size_t)row * KK + c0 + 4) =
            make_float4(o[4], o[5], o[6], o[7]);
    }
}

// ---------------------------------------------------------------------------
// Big GEMM: W[i][c] = sum_k beta_nd[i][k] * S[k][c]   (M=1024, N=16384, K=1024)
// grid (128, 8): x = 128-wide column tile, y = 128-wide row tile
// ---------------------------------------------------------------------------
__global__ __launch_bounds__(256) void gemm_beta_kernel(
    const float* __restrict__ beta, const float* __restrict__ S,
    float* __restrict__ W)
{
    __shared__ float Ap[32 * 132];   // beta^T panel [kk][i]
    __shared__ float Bp[32 * 128];   // S panel [kk][c]

    const int tid = threadIdx.x;
    const int tr  = tid >> 4, tc = tid & 15;
    const int r0  = tr * 8, c0 = tc * 8;
    const int i0  = blockIdx.y * 128;
    const size_t cbase = (size_t)blockIdx.x * 128;

    float acc[8][8];
    #pragma unroll
    for (int m = 0; m < 8; ++m)
        #pragma unroll
        for (int e = 0; e < 8; ++e) acc[m][e] = 0.f;

    for (int kp = 0; kp < 32; ++kp) {
        const int k0 = kp * 32;
        #pragma unroll
        for (int it = 0; it < 4; ++it) {
            int idx = it * 256 + tid;
            int r = idx >> 3;
            int kk = (idx & 7) << 2;
            int gi = i0 + r;
            float4 v = *(const float4*)(beta + (size_t)gi * NN + k0 + kk);
            // zero the diagonal of beta
            if (gi == k0 + kk + 0) v.x = 0.f;
            if (gi == k0 + kk + 1) v.y = 0.f;
            if (gi == k0 + kk + 2) v.z = 0.f;
            if (gi == k0 + kk + 3) v.w = 0.f;
            Ap[(kk + 0) * 132 + r] = v.x;
            Ap[(kk + 1) * 132 + r] = v.y;
            Ap[(kk + 2) * 132 + r] = v.z;
            Ap[(kk + 3) * 132 + r] = v.w;
        }
        #pragma unroll
        for (int it = 0; it < 4; ++it) {
            int idx = it * 256 + tid;
            int kk = idx >> 5;
            int c  = (idx & 31) << 2;
            *(float4*)&Bp[kk * 128 + c] =
                *(const float4*)(S + (size_t)(k0 + kk) * 16384 + cbase + c);
        }
        __syncthreads();
        #pragma unroll 8
        for (int kk = 0; kk < 32; ++kk) {
            float4 a0 = *(const float4*)&Ap[kk * 132 + r0];
            float4 a1 = *(const float4*)&Ap[kk * 132 + r0 + 4];
            float4 b0 = *(const float4*)&Bp[kk * 128 + c0];
            float4 b1 = *(const float4*)&Bp[kk * 128 + c0 + 4];
            float av[8] = {a0.x, a0.y, a0.z, a0.w, a1.x, a1.y, a1.z, a1.w};
            float bv[8] = {b0.x, b0.y, b0.z, b0.w, b1.x, b1.y, b1.z, b1.w};
            #pragma unroll
            for (int m = 0; m < 8; ++m)
                #pragma unroll
                for (int e = 0; e < 8; ++e)
                    acc[m][e] = fmaf(av[m], bv[e], acc[m][e]);
        }
        __syncthreads();
    }
    #pragma unroll
    for (int m = 0; m < 8; ++m) {
        *(float4*)(W + (size_t)(i0 + r0 + m) * 16384 + cbase + c0) =
            make_float4(acc[m][0], acc[m][1], acc[m][2], acc[m][3]);
        *(float4*)(W + (size_t)(i0 + r0 + m) * 16384 + cbase + c0 + 4) =
            make_float4(acc[m][4], acc[m][5], acc[m][6], acc[m][7]);
    }
}

// ---------------------------------------------------------------------------
// Batched 128x128 inverse, Gauss-Jordan with partial pivoting.
// One block per matrix; matrix lives in registers (thread owns 4 rows x 16 cols).
// ALL register-array indices are compile-time constants (rule #20): dynamic
// row/col selection is done with select chains / predicated writes, never
// a[runtime][...]. Previous version spilled 64 floats/thread to scratch
// (13 GB of HBM traffic, 2.6 ms).
// ---------------------------------------------------------------------------
__global__ __launch_bounds__(256) void invert_kernel(
    const float* __restrict__ Om, float* __restrict__ Inv)
{
    const int n   = blockIdx.x;
    const int tid = threadIdx.x;
    const int rg  = tid >> 3;   // 0..31  (4 rows each)
    const int cc  = tid & 7;    // 0..7   (16 cols each)
    const int r0  = rg << 2;
    const int c0  = cc << 4;
    const size_t base = (size_t)n * (KK * KK);

    float a[4][16];
    #pragma unroll
    for (int m = 0; m < 4; ++m)
        #pragma unroll
        for (int j4 = 0; j4 < 4; ++j4) {
            float4 v = *(const float4*)(Om + base + (size_t)(r0 + m) * KK + c0 + j4 * 4);
            a[m][j4 * 4 + 0] = v.x; a[m][j4 * 4 + 1] = v.y;
            a[m][j4 * 4 + 2] = v.z; a[m][j4 * 4 + 3] = v.w;
        }

    __shared__ float colk[128];
    __shared__ float rowk[128];
    __shared__ float rowswap[128];
    __shared__ int   perm[128];
    __shared__ int   piv_sh;
    __shared__ float pv_sh;

    for (int k = 0; k < 128; ++k) {
        const int kcc = k >> 4, kj = k & 15, krg = k >> 2, km = k & 3;
        // ---- publish current column k (16-way select, static indices) ----
        if (cc == kcc) {
            #pragma unroll
            for (int m = 0; m < 4; ++m) {
                float v = a[m][0];
                #pragma unroll
                for (int j = 1; j < 16; ++j) v = (kj == j) ? a[m][j] : v;
                colk[r0 + m] = v;
            }
        }
        __syncthreads();
        // ---- pivot search (wave 0) ----
        if (tid < 64) {
            float best = -1.f; int bi = k;
            for (int i = k + tid; i < 128; i += 64) {
                float v = fabsf(colk[i]);
                if (v > best) { best = v; bi = i; }
            }
            #pragma unroll
            for (int off = 32; off >= 1; off >>= 1) {
                float ov = __shfl_down(best, off);
                int   oi = __shfl_down(bi, off);
                if (ov > best) { best = ov; bi = oi; }
            }
            if (tid == 0) { piv_sh = bi; pv_sh = colk[bi]; perm[k] = bi; }
        }
        __syncthreads();
        const int   r      = piv_sh;
        const float pivinv = 1.0f / pv_sh;
        // ---- swap rows k and r (block-uniform branch) ----
        if (r != k) {
            const int rrg = r >> 2, rm = r & 3;
            if (rg == krg) {
                #pragma unroll
                for (int j = 0; j < 16; ++j) {
                    float t = a[0][j];
                    #pragma unroll
                    for (int m = 1; m < 4; ++m) t = (km == m) ? a[m][j] : t;
                    rowk[c0 + j] = t;
                }
            }
            if (rg == rrg) {
                #pragma unroll
                for (int j = 0; j < 16; ++j) {
                    float t = a[0][j];
                    #pragma unroll
                    for (int m = 1; m < 4; ++m) t = (rm == m) ? a[m][j] : t;
                    rowswap[c0 + j] = t;
                }
            }
            __syncthreads();
            if (rg == krg) {
                #pragma unroll
                for (int m = 0; m < 4; ++m)
                    #pragma unroll
                    for (int j = 0; j < 16; ++j)
                        if (m == km) a[m][j] = rowswap[c0 + j];
            }
            if (rg == rrg) {
                #pragma unroll
                for (int m = 0; m < 4; ++m)
                    #pragma unroll
                    for (int j = 0; j < 16; ++j)
                        if (m == rm) a[m][j] = rowk[c0 + j];
            }
            if (tid == 0) { float t = colk[k]; colk[k] = colk[r]; colk[r] = t; }
            __syncthreads();
        }
        // ---- scale pivot row (select + predicated writeback), publish ----
        if (rg == krg) {
            #pragma unroll
            for (int j = 0; j < 16; ++j) {
                const int jg = c0 + j;
                float t = a[0][j];
                #pragma unroll
                for (int m = 1; m < 4; ++m) t = (km == m) ? a[m][j] : t;
                float v = (jg == k) ? pivinv : t * pivinv;
                rowk[jg] = v;
                #pragma unroll
                for (int m = 0; m < 4; ++m)
                    if (m == km) a[m][j] = v;
            }
        }
        __syncthreads();
        // ---- rank-1 update of all other rows (static indices) ----
        float rk[16];
        #pragma unroll
        for (int j = 0; j < 16; ++j) rk[j] = rowk[c0 + j];
        #pragma unroll
        for (int m = 0; m < 4; ++m) {
            const int l = r0 + m;
            if (l == k) continue;   // predicated; body has static indices
            const float f = colk[l];
            #pragma unroll
            for (int j = 0; j < 16; ++j) {
                const int jg = c0 + j;
                float v = (jg == k) ? 0.f : a[m][j];
                a[m][j] = fmaf(-f, rk[j], v);
            }
        }
        __syncthreads();
    }

    // ---- column unscramble (undo row pivots) — LDS, not thread-local ----
    __shared__ int idxa_sh[128];
    __shared__ int pos_sh[128];
    if (tid < 128) idxa_sh[tid] = tid;
    __syncthreads();
    if (tid == 0) {
        for (int l = 127; l >= 0; --l) {
            int p = perm[l];
            if (p != l) { int t = idxa_sh[l]; idxa_sh[l] = idxa_sh[p]; idxa_sh[p] = t; }
        }
    }
    __syncthreads();
    if (tid < 128) pos_sh[idxa_sh[tid]] = tid;
    __syncthreads();
    float* dst = Inv + base;
    #pragma unroll
    for (int m = 0; m < 4; ++m)
        #pragma unroll
        for (int j = 0; j < 16; ++j)
            dst[(size_t)(r0 + m) * KK + pos_sh[c0 + j]] = a[m][j];
}

// ---------------------------------------------------------------------------
extern "C" void kernel_launch(void* const* d_in, const int* in_sizes, int n_in,
                              void* d_out, int out_size, void* d_ws, size_t ws_size,
                              hipStream_t stream)
{
    const float* beta  = (const float*)d_in[0];
    const float* omega = (const float*)d_in[1];
    const float* Lp    = (const float*)d_in[2];
    const float* Lq    = (const float*)d_in[3];
    const float* obs   = (const float*)d_in[4];
    float* out = (float*)d_out;

    const size_t MATE = (size_t)NN * KK * KK;  // elements of one (N,K,K) tensor
    float* S = (float*)d_ws;
    float* Wbuf = (ws_size >= 2 * MATE * sizeof(float)) ? (S + MATE) : out;
    float* Inv = S;  // reuse S space after the big GEMM consumed S

    // 1. S_n = Omega_n^T Lq_n Omega_n
    sandwich_kernel<false><<<dim3(NN), dim3(256), 0, stream>>>(
        Lq, omega, S, nullptr, nullptr, nullptr, nullptr);
    // 2. W = beta_nd @ S
    gemm_beta_kernel<<<dim3(128, 8), dim3(256), 0, stream>>>(beta, S, Wbuf);
    // 3. Inv_n = Omega_n^{-1}
    invert_kernel<<<dim3(NN), dim3(256), 0, stream>>>(omega, Inv);
    // 4. M_n = Inv_n^T W_n Inv_n + Lp_n + colsum_n * Lq_n + obs  (in-place safe)
    sandwich_kernel<true><<<dim3(NN), dim3(256), 0, stream>>>(
        Wbuf, Inv, out, Lp, Lq, obs, beta);
}